// Round 6
// baseline (43.039 us; speedup 1.0000x reference)
//
#include <hip/hip_runtime.h>

// Problem constants (match setup_inputs)
#define BB   2
#define CC   3
#define HH   192
#define WW   192
#define LL   19
#define PADR 9
#define HP   (HH + 2 * PADR)   // 210
#define WP   (WW + 2 * PADR)   // 210
#define HWN  (HH * WW)         // 36864
#define TAPS (LL * LL)         // 361

// Reflect-pad + rearrange image into (kb, HP, WP, float4) where component j
// holds channel-slot n = kb + BB*j (n = b*CC + c ordering of the reference).
__global__ __launch_bounds__(256) void pad_rearrange(
    const float* __restrict__ x, float4* __restrict__ img) {
    int idx = blockIdx.x * blockDim.x + threadIdx.x;
    const int total = BB * HP * WP;
    if (idx >= total) return;
    int xw  = idx % WP;
    int tmp = idx / WP;
    int y   = tmp % HP;
    int kb  = tmp / HP;
    int oy = y - PADR;
    oy = oy < 0 ? -oy : (oy >= HH ? 2 * HH - 2 - oy : oy);
    int ox = xw - PADR;
    ox = ox < 0 ? -ox : (ox >= WW ? 2 * WW - 2 - ox : ox);
    float v[3];
#pragma unroll
    for (int j = 0; j < 3; ++j) {
        int n = kb + BB * j;  // n = b*CC + c, with n % BB == kb
        v[j] = x[((size_t)n * HH + oy) * WW + ox];
    }
    img[idx] = make_float4(v[0], v[1], v[2], 0.0f);
}

// One wave per (kb, pixel) — round-0 structure. Kernel taps loaded with
// nontemporal hint (one-shot 106.5 MB stream must not evict the L1/L2-resident
// padded image). Tap coords advance incrementally (64 = 3*19+7) instead of
// per-iteration div/mod. Butterfly reduce; lane 0 stores 3 channels.
__global__ __launch_bounds__(256) void sv_blur(
    const float* __restrict__ kern, const float4* __restrict__ img,
    float* __restrict__ out) {
    int wid  = (blockIdx.x * blockDim.x + threadIdx.x) >> 6;  // wave id
    int lane = threadIdx.x & 63;
    int p  = wid % HWN;
    int kb = wid / HWN;
    int h = p / WW, w = p % WW;
    const float*  kbase = kern + (size_t)(kb * HWN + p) * TAPS;
    const float4* ibase = img + ((size_t)kb * HP + h) * WP + w;

    // tap t = lane + 64*it; ki = t/19, kj = t%19 tracked incrementally
    int ki   = lane / LL;
    int kj   = lane % LL;
    int ioff = ki * WP + kj;

    float a0 = 0.f, a1 = 0.f, a2 = 0.f;
#pragma unroll
    for (int it = 0; it < 6; ++it) {
        if (ki < LL) {   // equivalent to t < 361
            float  kv = __builtin_nontemporal_load(kbase + lane + (it << 6));
            float4 iv = ibase[ioff];
            a0 = fmaf(kv, iv.x, a0);
            a1 = fmaf(kv, iv.y, a1);
            a2 = fmaf(kv, iv.z, a2);
        }
        // advance tap by 64 = 3 rows + 7 cols
        if (kj >= LL - 7) { ki += 4; kj -= LL - 7; ioff += 4 * WP - (LL - 7); }
        else              { ki += 3; kj += 7;      ioff += 3 * WP + 7; }
    }
#pragma unroll
    for (int m = 32; m; m >>= 1) {
        a0 += __shfl_xor(a0, m, 64);
        a1 += __shfl_xor(a1, m, 64);
        a2 += __shfl_xor(a2, m, 64);
    }
    if (lane == 0) {
        out[(size_t)(kb + 0 * BB) * HWN + p] = a0;
        out[(size_t)(kb + 1 * BB) * HWN + p] = a1;
        out[(size_t)(kb + 2 * BB) * HWN + p] = a2;
    }
}

// Fallback (no workspace): inline reflect, 3 scalar image loads per tap.
__global__ __launch_bounds__(256) void sv_blur_nows(
    const float* __restrict__ kern, const float* __restrict__ x,
    float* __restrict__ out) {
    int wid  = (blockIdx.x * blockDim.x + threadIdx.x) >> 6;
    int lane = threadIdx.x & 63;
    int p  = wid % HWN;
    int kb = wid / HWN;
    int h = p / WW, w = p % WW;
    const float* kbase = kern + (size_t)(kb * HWN + p) * TAPS;
    float a[3] = {0.f, 0.f, 0.f};
#pragma unroll
    for (int it = 0; it < 6; ++it) {
        int t = lane + 64 * it;
        if (t < TAPS) {
            float kv = kbase[t];
            int ki = t / LL, kj = t % LL;
            int oy = h + ki - PADR;
            oy = oy < 0 ? -oy : (oy >= HH ? 2 * HH - 2 - oy : oy);
            int ox = w + kj - PADR;
            ox = ox < 0 ? -ox : (ox >= WW ? 2 * WW - 2 - ox : ox);
#pragma unroll
            for (int j = 0; j < 3; ++j) {
                int n = kb + BB * j;
                a[j] = fmaf(kv, x[((size_t)n * HH + oy) * WW + ox], a[j]);
            }
        }
    }
#pragma unroll
    for (int m = 32; m; m >>= 1) {
        a[0] += __shfl_xor(a[0], m, 64);
        a[1] += __shfl_xor(a[1], m, 64);
        a[2] += __shfl_xor(a[2], m, 64);
    }
    if (lane == 0) {
#pragma unroll
        for (int j = 0; j < 3; ++j)
            out[(size_t)(kb + j * BB) * HWN + p] = a[j];
    }
}

extern "C" void kernel_launch(void* const* d_in, const int* in_sizes, int n_in,
                              void* d_out, int out_size, void* d_ws, size_t ws_size,
                              hipStream_t stream) {
    const float* x    = (const float*)d_in[0];
    const float* kern = (const float*)d_in[1];
    float*       out  = (float*)d_out;

    const size_t need = (size_t)BB * HP * WP * sizeof(float4);  // ~1.41 MB
    const int nwaves  = BB * HWN;          // 73728
    const int nblocks = nwaves / 4;        // 256 thr = 4 waves per block

    if (ws_size >= need) {
        float4* img = (float4*)d_ws;
        const int ptotal = BB * HP * WP;
        pad_rearrange<<<(ptotal + 255) / 256, 256, 0, stream>>>(x, img);
        sv_blur<<<nblocks, 256, 0, stream>>>(kern, img, out);
    } else {
        sv_blur_nows<<<nblocks, 256, 0, stream>>>(kern, x, out);
    }
}

// Round 7
// 31.817 us; speedup vs baseline: 1.3527x; 1.3527x over previous
//
#include <hip/hip_runtime.h>

// Problem constants (match setup_inputs)
#define BB   2
#define CC   3
#define HH   192
#define WW   192
#define LL   19
#define PADR 9
#define HP   (HH + 2 * PADR)   // 210
#define WP   (WW + 2 * PADR)   // 210
#define HWN  (HH * WW)         // 36864
#define TAPS (LL * LL)         // 361

// Reflect-pad + rearrange image into (kb, HP, WP, float4) where component j
// holds channel-slot n = kb + BB*j (n = b*CC + c ordering of the reference).
__global__ __launch_bounds__(256) void pad_rearrange(
    const float* __restrict__ x, float4* __restrict__ img) {
    int idx = blockIdx.x * blockDim.x + threadIdx.x;
    const int total = BB * HP * WP;
    if (idx >= total) return;
    int xw  = idx % WP;
    int tmp = idx / WP;
    int y   = tmp % HP;
    int kb  = tmp / HP;
    int oy = y - PADR;
    oy = oy < 0 ? -oy : (oy >= HH ? 2 * HH - 2 - oy : oy);
    int ox = xw - PADR;
    ox = ox < 0 ? -ox : (ox >= WW ? 2 * WW - 2 - ox : ox);
    float v[3];
#pragma unroll
    for (int j = 0; j < 3; ++j) {
        int n = kb + BB * j;  // n = b*CC + c, with n % BB == kb
        v[j] = x[((size_t)n * HH + oy) * WW + ox];
    }
    img[idx] = make_float4(v[0], v[1], v[2], 0.0f);
}

// One wave per (kb, pixel) — round-0 proven structure. Changes vs R0:
//  (1) iterations 0..4 are provably full (lane+256 <= 319 < 361): no mask;
//      only the 6th partial iteration (taps 320..360) is predicated.
//  (2) one store instruction: lanes 0/1/2 each store their channel.
__global__ __launch_bounds__(256) void sv_blur(
    const float* __restrict__ kern, const float4* __restrict__ img,
    float* __restrict__ out) {
    int wid  = (blockIdx.x * blockDim.x + threadIdx.x) >> 6;  // wave id
    int lane = threadIdx.x & 63;
    int p  = wid % HWN;
    int kb = wid / HWN;
    int h = p / WW, w = p % WW;
    const float*  kbase = kern + (size_t)(kb * HWN + p) * TAPS;
    const float4* ibase = img + ((size_t)kb * HP + h) * WP + w;
    float a0 = 0.f, a1 = 0.f, a2 = 0.f;
#pragma unroll
    for (int it = 0; it < 5; ++it) {      // always-valid taps
        int t = lane + (it << 6);
        float  kv = kbase[t];
        int    ki = t / LL, kj = t % LL;
        float4 iv = ibase[ki * WP + kj];
        a0 = fmaf(kv, iv.x, a0);
        a1 = fmaf(kv, iv.y, a1);
        a2 = fmaf(kv, iv.z, a2);
    }
    {                                      // partial tail: taps 320..360
        int t = lane + 320;
        if (t < TAPS) {
            float  kv = kbase[t];
            int    ki = t / LL, kj = t % LL;
            float4 iv = ibase[ki * WP + kj];
            a0 = fmaf(kv, iv.x, a0);
            a1 = fmaf(kv, iv.y, a1);
            a2 = fmaf(kv, iv.z, a2);
        }
    }
#pragma unroll
    for (int m = 32; m; m >>= 1) {
        a0 += __shfl_xor(a0, m, 64);
        a1 += __shfl_xor(a1, m, 64);
        a2 += __shfl_xor(a2, m, 64);
    }
    if (lane < 3) {
        float v = lane == 0 ? a0 : (lane == 1 ? a1 : a2);
        out[(size_t)(kb + lane * BB) * HWN + p] = v;
    }
}

// Fallback (no workspace): inline reflect, 3 scalar image loads per tap.
__global__ __launch_bounds__(256) void sv_blur_nows(
    const float* __restrict__ kern, const float* __restrict__ x,
    float* __restrict__ out) {
    int wid  = (blockIdx.x * blockDim.x + threadIdx.x) >> 6;
    int lane = threadIdx.x & 63;
    int p  = wid % HWN;
    int kb = wid / HWN;
    int h = p / WW, w = p % WW;
    const float* kbase = kern + (size_t)(kb * HWN + p) * TAPS;
    float a[3] = {0.f, 0.f, 0.f};
#pragma unroll
    for (int it = 0; it < 6; ++it) {
        int t = lane + 64 * it;
        if (t < TAPS) {
            float kv = kbase[t];
            int ki = t / LL, kj = t % LL;
            int oy = h + ki - PADR;
            oy = oy < 0 ? -oy : (oy >= HH ? 2 * HH - 2 - oy : oy);
            int ox = w + kj - PADR;
            ox = ox < 0 ? -ox : (ox >= WW ? 2 * WW - 2 - ox : ox);
#pragma unroll
            for (int j = 0; j < 3; ++j) {
                int n = kb + BB * j;
                a[j] = fmaf(kv, x[((size_t)n * HH + oy) * WW + ox], a[j]);
            }
        }
    }
#pragma unroll
    for (int m = 32; m; m >>= 1) {
        a[0] += __shfl_xor(a[0], m, 64);
        a[1] += __shfl_xor(a[1], m, 64);
        a[2] += __shfl_xor(a[2], m, 64);
    }
    if (lane == 0) {
#pragma unroll
        for (int j = 0; j < 3; ++j)
            out[(size_t)(kb + j * BB) * HWN + p] = a[j];
    }
}

extern "C" void kernel_launch(void* const* d_in, const int* in_sizes, int n_in,
                              void* d_out, int out_size, void* d_ws, size_t ws_size,
                              hipStream_t stream) {
    const float* x    = (const float*)d_in[0];
    const float* kern = (const float*)d_in[1];
    float*       out  = (float*)d_out;

    const size_t need = (size_t)BB * HP * WP * sizeof(float4);  // ~1.41 MB
    const int nwaves  = BB * HWN;          // 73728
    const int nblocks = nwaves / 4;        // 256 thr = 4 waves per block

    if (ws_size >= need) {
        float4* img = (float4*)d_ws;
        const int ptotal = BB * HP * WP;
        pad_rearrange<<<(ptotal + 255) / 256, 256, 0, stream>>>(x, img);
        sv_blur<<<nblocks, 256, 0, stream>>>(kern, img, out);
    } else {
        sv_blur_nows<<<nblocks, 256, 0, stream>>>(kern, x, out);
    }
}